// Round 7
// baseline (179.383 us; speedup 1.0000x reference)
//
#include <hip/hip_runtime.h>
#include <math.h>

#define S_LEN 2048
#define DMODEL 512
#define NHEAD 8
#define DHEAD 64
#define LN_EPS 1e-5f

typedef __bf16 bf16;
typedef __bf16 bf16x8 __attribute__((ext_vector_type(8)));
typedef __bf16 bf16x4 __attribute__((ext_vector_type(4)));
typedef __bf16 bf16x2 __attribute__((ext_vector_type(2)));
typedef float f32x4 __attribute__((ext_vector_type(4)));

__device__ __forceinline__ float wave_reduce_sum(float x) {
#pragma unroll
  for (int off = 32; off > 0; off >>= 1) x += __shfl_xor(x, off);
  return x;
}

// ---- 32x32 transpose+cast tile helper ---------------------------------------
__device__ __forceinline__ void transpose_tile(const float* __restrict__ W,
                                               bf16* __restrict__ WT, int K,
                                               int N, int bx, int by,
                                               float (*t)[33], int tid) {
  const int c = tid & 31, r8 = tid >> 5;
  const int n0 = bx * 32, k0 = by * 32;
#pragma unroll
  for (int it = 0; it < 4; it++) {
    const int r = r8 + it * 8;
    t[r][c] = W[(size_t)(k0 + r) * N + n0 + c];
  }
  __syncthreads();
#pragma unroll
  for (int it = 0; it < 4; it++) {
    const int r = r8 + it * 8;
    WT[(size_t)(n0 + r) * K + k0 + c] = (bf16)t[c][r];
  }
}

// ---------------- prep1: LN (blocks 0..2047) + wqkvT (2048..2815) -----------
__global__ __launch_bounds__(256) void prep1_kernel(
    const float* __restrict__ x, const float* __restrict__ ln_g,
    const float* __restrict__ ln_b, const float* __restrict__ w_qkv,
    bf16* __restrict__ xn, bf16* __restrict__ wqkvT) {
  __shared__ float t[32][33];
  __shared__ float red[2][4];
  int b = blockIdx.x;
  const int tid = threadIdx.x;
  if (b < 2048) {
    const float2 v = ((const float2*)(x + (size_t)b * DMODEL))[tid];
    float s = v.x + v.y;
    float s2 = v.x * v.x + v.y * v.y;
    s = wave_reduce_sum(s);
    s2 = wave_reduce_sum(s2);
    const int wv = tid >> 6, ln = tid & 63;
    if (ln == 0) { red[0][wv] = s; red[1][wv] = s2; }
    __syncthreads();
    s = red[0][0] + red[0][1] + red[0][2] + red[0][3];
    s2 = red[1][0] + red[1][1] + red[1][2] + red[1][3];
    const float mu = s * (1.0f / DMODEL);
    const float var = s2 * (1.0f / DMODEL) - mu * mu;
    const float rs = rsqrtf(var + LN_EPS);
    const float2 gg = ((const float2*)ln_g)[tid];
    const float2 bb = ((const float2*)ln_b)[tid];
    bf16x2 o;
    o[0] = (bf16)((v.x - mu) * rs * gg.x + bb.x);
    o[1] = (bf16)((v.y - mu) * rs * gg.y + bb.y);
    ((bf16x2*)(xn + (size_t)b * DMODEL))[tid] = o;
    return;
  }
  b -= 2048;
  transpose_tile(w_qkv, wqkvT, 512, 1536, b % 48, b / 48, t, tid);
}

// ---------------- LDS-free wave GEMM core ------------------------------------
// Wave computes a 64 x (JT*16) output tile. A[M][ldk], BT[N][ldk] both
// k-contiguous: each lane's MFMA fragment is one 16-B global load. K-loop is
// fully unrolled -> compiler pipelines loads across MFMAs (fine-grained vmcnt),
// no barriers anywhere.
template <int KLOOP, int JT>
__device__ __forceinline__ void gemm_core(const bf16* __restrict__ A,
                                          const bf16* __restrict__ BT,
                                          int ldk, int waveRow, int waveCol,
                                          int lr, int kg, f32x4 (&acc)[4][JT]) {
  const bf16* ap = A + (size_t)(waveRow + lr) * ldk + kg * 8;
  const bf16* bp = BT + (size_t)(waveCol + lr) * ldk + kg * 8;
  const size_t rstride = (size_t)16 * ldk;
#pragma unroll
  for (int kk = 0; kk < KLOOP; kk += 32) {
    bf16x8 af[4], bfv[JT];
#pragma unroll
    for (int i = 0; i < 4; i++)
      af[i] = *(const bf16x8*)(ap + kk + i * rstride);
#pragma unroll
    for (int j = 0; j < JT; j++)
      bfv[j] = *(const bf16x8*)(bp + kk + j * rstride);
#pragma unroll
    for (int i = 0; i < 4; i++)
#pragma unroll
      for (int j = 0; j < JT; j++)
        acc[i][j] = __builtin_amdgcn_mfma_f32_16x16x32_bf16(af[i], bfv[j],
                                                            acc[i][j], 0, 0, 0);
  }
}

// ------ QKV GEMM (blocks 0..191) + w_out/w1/w2 transposes (192..2495) -------
// Block tile 128x128 (4 waves 2x2, wave 64x64). V cols (>=1024) -> vT^T.
__global__ __launch_bounds__(256, 1) void qkv_kernel(
    const bf16* __restrict__ A, const bf16* __restrict__ BT,
    const float* __restrict__ bias, bf16* __restrict__ qkvb,
    bf16* __restrict__ vT, const float* __restrict__ w_out,
    const float* __restrict__ w1, const float* __restrict__ w2,
    bf16* __restrict__ woutT, bf16* __restrict__ w1T, bf16* __restrict__ w2T) {
  __shared__ float t[32][33];
  int b = blockIdx.x;
  const int tid = threadIdx.x;

  if (b >= 192) {  // weight transposes, concurrent with the GEMM
    b -= 192;
    if (b < 256)       transpose_tile(w_out, woutT, 512, 512, b % 16, b / 16, t, tid);
    else if (b < 1280) { b -= 256;  transpose_tile(w1, w1T, 512, 2048, b % 64, b / 64, t, tid); }
    else               { b -= 1280; transpose_tile(w2, w2T, 2048, 512, b % 16, b / 16, t, tid); }
    return;
  }

  const int wave = tid >> 6, lane = tid & 63;
  const int lr = lane & 15, kg = lane >> 4;
  const int wm = wave & 1, wn = wave >> 1;
  const int waveRow = (b / 12) * 128 + wm * 64;
  const int waveCol = (b % 12) * 128 + wn * 64;

  f32x4 acc[4][4] = {};
  gemm_core<512, 4>(A, BT, 512, waveRow, waveCol, lr, kg, acc);

#pragma unroll
  for (int j = 0; j < 4; j++) {
    const int colT = waveCol + j * 16;
    const int col = colT + lr;
    const float bs = bias[col];
    if (colT >= 1024) {  // V region -> vT[(col-1024)][row]
      bf16* dst = vT + (size_t)(col - 1024) * S_LEN;
#pragma unroll
      for (int i = 0; i < 4; i++) {
        bf16x4 p;
#pragma unroll
        for (int r = 0; r < 4; r++) p[r] = (bf16)(acc[i][j][r] + bs);
        *(bf16x4*)(dst + waveRow + i * 16 + kg * 4) = p;
      }
    } else {
#pragma unroll
      for (int i = 0; i < 4; i++)
#pragma unroll
        for (int r = 0; r < 4; r++) {
          const size_t row = waveRow + i * 16 + kg * 4 + r;
          qkvb[row * 1536 + col] = (bf16)(acc[i][j][r] + bs);
        }
    }
  }
}

// ------- out-proj: block tile 128x64 (wave 64x32), bias+res -> f32+bf16 -----
__global__ __launch_bounds__(256, 1) void outproj_kernel(
    const bf16* __restrict__ A, const bf16* __restrict__ BT,
    const float* __restrict__ bias, const float* __restrict__ res,
    float* __restrict__ Cf, bf16* __restrict__ Cb) {
  const int b = blockIdx.x;
  const int tid = threadIdx.x;
  const int wave = tid >> 6, lane = tid & 63;
  const int lr = lane & 15, kg = lane >> 4;
  const int wm = wave & 1, wn = wave >> 1;
  const int waveRow = (b / 8) * 128 + wm * 64;
  const int waveCol = (b % 8) * 64 + wn * 32;

  f32x4 acc[4][2] = {};
  gemm_core<512, 2>(A, BT, 512, waveRow, waveCol, lr, kg, acc);

#pragma unroll
  for (int j = 0; j < 2; j++) {
    const int col = waveCol + j * 16 + lr;
    const float bs = bias[col];
#pragma unroll
    for (int i = 0; i < 4; i++)
#pragma unroll
      for (int r = 0; r < 4; r++) {
        const size_t row = waveRow + i * 16 + kg * 4 + r;
        const float v = acc[i][j][r] + bs + res[row * DMODEL + col];
        Cf[row * DMODEL + col] = v;
        Cb[row * DMODEL + col] = (bf16)v;
      }
  }
}

// ------- FFN1: block tile 128x128 (wave 64x64), bias+GELU -> bf16 -----------
__global__ __launch_bounds__(256, 1) void ffn1_kernel(
    const bf16* __restrict__ A, const bf16* __restrict__ BT,
    const float* __restrict__ bias, bf16* __restrict__ Cb) {
  const int b = blockIdx.x;
  const int tid = threadIdx.x;
  const int wave = tid >> 6, lane = tid & 63;
  const int lr = lane & 15, kg = lane >> 4;
  const int wm = wave & 1, wn = wave >> 1;
  const int waveRow = (b / 16) * 128 + wm * 64;
  const int waveCol = (b % 16) * 128 + wn * 64;

  f32x4 acc[4][4] = {};
  gemm_core<512, 4>(A, BT, 512, waveRow, waveCol, lr, kg, acc);

#pragma unroll
  for (int j = 0; j < 4; j++) {
    const int col = waveCol + j * 16 + lr;
    const float bs = bias[col];
#pragma unroll
    for (int i = 0; i < 4; i++)
#pragma unroll
      for (int r = 0; r < 4; r++) {
        const size_t row = waveRow + i * 16 + kg * 4 + r;
        float v = acc[i][j][r] + bs;
        v = 0.5f * v * (1.0f + erff(v * 0.70710678118654752f));
        Cb[row * 2048 + col] = (bf16)v;
      }
  }
}

// ------- FFN2 split-K=2: block tile 128x64, atomic add into d_out -----------
// d_out already holds `out` (the residual). Half 0 adds bias.
__global__ __launch_bounds__(256, 1) void ffn2_kernel(
    const bf16* __restrict__ A, const bf16* __restrict__ BT,
    const float* __restrict__ bias, float* __restrict__ out) {
  const int b = blockIdx.x;
  const int kh = b & 1;
  const int tile = b >> 1;  // 0..127
  const int tid = threadIdx.x;
  const int wave = tid >> 6, lane = tid & 63;
  const int lr = lane & 15, kg = lane >> 4;
  const int wm = wave & 1, wn = wave >> 1;
  const int waveRow = (tile / 8) * 128 + wm * 64;
  const int waveCol = (tile % 8) * 64 + wn * 32;

  f32x4 acc[4][2] = {};
  gemm_core<1024, 2>(A + kh * 1024, BT + kh * 1024, 2048, waveRow, waveCol,
                     lr, kg, acc);

#pragma unroll
  for (int j = 0; j < 2; j++) {
    const int col = waveCol + j * 16 + lr;
    const float bs = (kh == 0) ? bias[col] : 0.0f;
#pragma unroll
    for (int i = 0; i < 4; i++)
#pragma unroll
      for (int r = 0; r < 4; r++) {
        const size_t row = waveRow + i * 16 + kg * 4 + r;
        unsafeAtomicAdd(&out[row * DMODEL + col], acc[i][j][r] + bs);
      }
  }
}

// ---------------- fused MFMA local attention (unchanged, verified) ----------
__global__ __launch_bounds__(256) void attn_fused(const bf16* __restrict__ qkvb,
                                                  const bf16* __restrict__ vT,
                                                  bf16* __restrict__ attnb) {
  __shared__ bf16 Kl[192][72];
  __shared__ bf16 Vt[64][200];
  __shared__ bf16 Ql[64][72];

  const int tid = threadIdx.x;
  const int s0 = blockIdx.x * 64;
  const int hc = blockIdx.y * DHEAD;

  {
    const int row = tid >> 2, c0 = (tid & 3) * 16;
    const bf16* src = qkvb + (size_t)(s0 + row) * 1536 + hc + c0;
    *(bf16x8*)&Ql[row][c0] = *(const bf16x8*)src;
    *(bf16x8*)&Ql[row][c0 + 8] = *(const bf16x8*)(src + 8);
  }
#pragma unroll
  for (int it = 0; it < 3; it++) {
    const int row = it * 64 + (tid >> 2), c0 = (tid & 3) * 16;
    const int p = s0 - 64 + row;
    bf16x8 a, b;
    if (p >= 0 && p < S_LEN) {
      const bf16* src = qkvb + (size_t)p * 1536 + 512 + hc + c0;
      a = *(const bf16x8*)src;
      b = *(const bf16x8*)(src + 8);
    } else {
#pragma unroll
      for (int j = 0; j < 8; j++) { a[j] = (bf16)0.f; b[j] = (bf16)0.f; }
    }
    *(bf16x8*)&Kl[row][c0] = a;
    *(bf16x8*)&Kl[row][c0 + 8] = b;
  }
  {
    const int d = tid >> 2, r0 = (tid & 3) * 48;
    const bf16* src = vT + (size_t)(hc + d) * S_LEN;
#pragma unroll
    for (int i = 0; i < 6; i++) {
      const int p0 = s0 - 64 + r0 + i * 8;
      bf16x8 v;
      if (p0 >= 0 && p0 + 8 <= S_LEN) {
        v = *(const bf16x8*)(src + p0);
      } else {
#pragma unroll
        for (int j = 0; j < 8; j++) {
          const int p = p0 + j;
          v[j] = (p >= 0 && p < S_LEN) ? src[p] : (bf16)0.f;
        }
      }
      *(bf16x8*)&Vt[d][r0 + i * 8] = v;
    }
  }
  __syncthreads();

  const int wv = tid >> 6, lane = tid & 63;
  const int lr = lane & 15, kg = lane >> 4;

  f32x4 c[12] = {};
#pragma unroll
  for (int step = 0; step < 2; step++) {
    const bf16x8 qf = *(const bf16x8*)&Ql[wv * 16 + lr][step * 32 + kg * 8];
#pragma unroll
    for (int t = 0; t < 12; t++) {
      const bf16x8 kf = *(const bf16x8*)&Kl[t * 16 + lr][step * 32 + kg * 8];
      c[t] = __builtin_amdgcn_mfma_f32_16x16x32_bf16(qf, kf, c[t], 0, 0, 0);
    }
  }

  float e[12][4];
  float inv[4];
#pragma unroll
  for (int rr = 0; rr < 4; rr++) {
    const int q = wv * 16 + kg * 4 + rr;
    float m = -1e30f;
#pragma unroll
    for (int t = 0; t < 12; t++) {
      const int col = t * 16 + lr;
      if (col >= q && col <= q + 128) m = fmaxf(m, c[t][rr] * 0.125f);
    }
#pragma unroll
    for (int off = 1; off < 16; off <<= 1) m = fmaxf(m, __shfl_xor(m, off));
    float sum = 0.f;
#pragma unroll
    for (int t = 0; t < 12; t++) {
      const int col = t * 16 + lr;
      const bool valid = (col >= q) && (col <= q + 128);
      const float ev = valid ? __expf(c[t][rr] * 0.125f - m) : 0.f;
      e[t][rr] = ev;
      sum += ev;
    }
#pragma unroll
    for (int off = 1; off < 16; off <<= 1) sum += __shfl_xor(sum, off);
    inv[rr] = 1.f / sum;
  }

  __syncthreads();

  bf16* Pl = (bf16*)Kl + wv * (16 * 200);
#pragma unroll
  for (int rr = 0; rr < 4; rr++)
#pragma unroll
    for (int t = 0; t < 12; t++)
      Pl[(kg * 4 + rr) * 200 + t * 16 + lr] = (bf16)(e[t][rr] * inv[rr]);

  f32x4 o[4] = {};
#pragma unroll
  for (int step = 0; step < 6; step++) {
    const bf16x8 pf = *(const bf16x8*)&Pl[lr * 200 + step * 32 + kg * 8];
#pragma unroll
    for (int jt = 0; jt < 4; jt++) {
      const bf16x8 vf = *(const bf16x8*)&Vt[jt * 16 + lr][step * 32 + kg * 8];
      o[jt] = __builtin_amdgcn_mfma_f32_16x16x32_bf16(pf, vf, o[jt], 0, 0, 0);
    }
  }

#pragma unroll
  for (int jt = 0; jt < 4; jt++)
#pragma unroll
    for (int rr = 0; rr < 4; rr++) {
      const int q = wv * 16 + kg * 4 + rr;
      attnb[(size_t)(s0 + q) * DMODEL + hc + jt * 16 + lr] = (bf16)o[jt][rr];
    }
}

// ---------------- launch ----------------
extern "C" void kernel_launch(void* const* d_in, const int* in_sizes, int n_in,
                              void* d_out, int out_size, void* d_ws, size_t ws_size,
                              hipStream_t stream) {
  const float* x     = (const float*)d_in[0];
  const float* w_qkv = (const float*)d_in[1];
  const float* b_qkv = (const float*)d_in[2];
  const float* w_out = (const float*)d_in[3];
  const float* b_out = (const float*)d_in[4];
  const float* ln_g  = (const float*)d_in[5];
  const float* ln_b  = (const float*)d_in[6];
  const float* w1    = (const float*)d_in[7];
  const float* b1    = (const float*)d_in[8];
  const float* w2    = (const float*)d_in[9];
  const float* b2    = (const float*)d_in[10];
  float* out = (float*)d_out;

  char* w = (char*)d_ws;
  const size_t MB = 1u << 20;
  bf16* xn    = (bf16*)(w + 0);           // [0,2) MB
  bf16* attnb = (bf16*)(w + 0);           // alias xn (dead after QKV)
  bf16* qkvb  = (bf16*)(w + 2 * MB);      // [2,8) MB
  bf16* outb  = (bf16*)(w + 2 * MB);      // alias qkvb (dead after attention)
  bf16* vT    = (bf16*)(w + 8 * MB);      // [8,10) MB
  bf16* h1    = (bf16*)(w + 10 * MB);     // [10,18) MB
  bf16* wqkvT = (bf16*)(w + 18 * MB);     // 1.5 MB
  bf16* woutT = (bf16*)(w + 19 * MB + 512 * 1024);  // 0.5 MB
  bf16* w1T   = (bf16*)(w + 20 * MB);     // 2 MB
  bf16* w2T   = (bf16*)(w + 22 * MB);     // 2 MB

  // 1. LN (2048) + wqkvT (768)
  prep1_kernel<<<2816, 256, 0, stream>>>(x, ln_g, ln_b, w_qkv, xn, wqkvT);
  // 2. QKV GEMM (192) + w_out/w1/w2 transposes (2304)
  qkv_kernel<<<2496, 256, 0, stream>>>(xn, wqkvT, b_qkv, qkvb, vT,
                                       w_out, w1, w2, woutT, w1T, w2T);
  // 3. fused attention
  attn_fused<<<dim3(32, 8), 256, 0, stream>>>(qkvb, vT, attnb);
  // 4. out-proj + residual(x) -> f32 out + bf16 outb (128 blocks)
  outproj_kernel<<<128, 256, 0, stream>>>(attnb, woutT, b_out, x, out, outb);
  // 5. FFN1 + GELU -> bf16 h1 (256 blocks)
  ffn1_kernel<<<256, 256, 0, stream>>>(outb, w1T, b1, h1);
  // 6. FFN2 split-K=2, atomic accumulate into d_out (256 blocks)
  ffn2_kernel<<<256, 256, 0, stream>>>(h1, w2T, b2, out);
}

// Round 8
// 139.969 us; speedup vs baseline: 1.2816x; 1.2816x over previous
//
#include <hip/hip_runtime.h>
#include <math.h>

#define S_LEN 2048
#define DMODEL 512
#define NHEAD 8
#define DHEAD 64
#define LN_EPS 1e-5f

typedef __bf16 bf16;
typedef __bf16 bf16x8 __attribute__((ext_vector_type(8)));
typedef __bf16 bf16x4 __attribute__((ext_vector_type(4)));
typedef __bf16 bf16x2 __attribute__((ext_vector_type(2)));
typedef float f32x4 __attribute__((ext_vector_type(4)));

__device__ __forceinline__ float wave_reduce_sum(float x) {
#pragma unroll
  for (int off = 32; off > 0; off >>= 1) x += __shfl_xor(x, off);
  return x;
}

// ---------------- prep: LN (blocks 0..2047) + weight transposes -------------
__global__ __launch_bounds__(256) void prep_kernel(
    const float* __restrict__ x, const float* __restrict__ ln_g,
    const float* __restrict__ ln_b, const float* __restrict__ w_qkv,
    const float* __restrict__ w_out, const float* __restrict__ w1,
    const float* __restrict__ w2, bf16* __restrict__ xn,
    bf16* __restrict__ wqkvT, bf16* __restrict__ woutT,
    bf16* __restrict__ w1T, bf16* __restrict__ w2T) {
  __shared__ float t[32][33];
  int b = blockIdx.x;
  const int tid = threadIdx.x;
  if (b < 2048) {
    const float2 v = ((const float2*)(x + (size_t)b * DMODEL))[tid];
    float s = v.x + v.y;
    float s2 = v.x * v.x + v.y * v.y;
    s = wave_reduce_sum(s);
    s2 = wave_reduce_sum(s2);
    __shared__ float red[2][4];
    const int wv = tid >> 6, ln = tid & 63;
    if (ln == 0) { red[0][wv] = s; red[1][wv] = s2; }
    __syncthreads();
    s = red[0][0] + red[0][1] + red[0][2] + red[0][3];
    s2 = red[1][0] + red[1][1] + red[1][2] + red[1][3];
    const float mu = s * (1.0f / DMODEL);
    const float var = s2 * (1.0f / DMODEL) - mu * mu;
    const float rs = rsqrtf(var + LN_EPS);
    const float2 gg = ((const float2*)ln_g)[tid];
    const float2 bb = ((const float2*)ln_b)[tid];
    bf16x2 o;
    o[0] = (bf16)((v.x - mu) * rs * gg.x + bb.x);
    o[1] = (bf16)((v.y - mu) * rs * gg.y + bb.y);
    ((bf16x2*)(xn + (size_t)b * DMODEL))[tid] = o;
    return;
  }
  b -= 2048;
  const float* W; bf16* WT; int K, N, bx, by;
  if (b < 768)       { W = w_qkv; WT = wqkvT; K = 512;  N = 1536; bx = b % 48; by = b / 48; }
  else if (b < 1024) { b -= 768;  W = w_out; WT = woutT; K = 512;  N = 512;  bx = b % 16; by = b / 16; }
  else if (b < 2048) { b -= 1024; W = w1;    WT = w1T;   K = 512;  N = 2048; bx = b % 64; by = b / 64; }
  else               { b -= 2048; W = w2;    WT = w2T;   K = 2048; N = 512;  bx = b % 16; by = b / 16; }
  const int c = tid & 31, r8 = tid >> 5;
  const int n0 = bx * 32, k0 = by * 32;
#pragma unroll
  for (int it = 0; it < 4; it++) {
    const int r = r8 + it * 8;
    t[r][c] = W[(size_t)(k0 + r) * N + n0 + c];
  }
  __syncthreads();
#pragma unroll
  for (int it = 0; it < 4; it++) {
    const int r = r8 + it * 8;
    WT[(size_t)(n0 + r) * K + k0 + c] = (bf16)t[c][r];
  }
}

// ---------------- mmC: 64x64 tile, BK=64, double-buffered -------------------
// MODE 4 = QKV: bias -> bf16 qkvb for cols<1024 (vectorized via LDS repack);
//              V cols (>=1024, block-uniform) write vT transposed.
// MODE 2 = bias + exact GELU -> bf16 (vectorized via LDS repack).
// SPLITK: if >0, this kernel computes K-half `kh` of a K=2*SPLITK GEMM and
// atomically accumulates f32 into `outF` (bias added only on kh==0).
template <int MODE, int SPLITK>
__global__ __launch_bounds__(256) void mmC_kernel(const bf16* __restrict__ A,
                                                  const bf16* __restrict__ BT,
                                                  const float* __restrict__ bias,
                                                  bf16* __restrict__ Cb,
                                                  bf16* __restrict__ vT,
                                                  float* __restrict__ outF,
                                                  int N, int K, int gx) {
  __shared__ bf16 As[2][64 * 64];   // 8 KB x2 (reused as epilogue scratch)
  __shared__ bf16 Bs[2][64 * 64];
  const int tid = threadIdx.x;
  int b = blockIdx.x;
  int kh = 0;
  if (SPLITK > 0) { kh = b & 1; b >>= 1; }
  const int wave = tid >> 6, lane = tid & 63;
  const int lr = lane & 15, kg = lane >> 4;
  const int wm = wave & 1, wn = wave >> 1;
  const int rowBase = (b / gx) * 64, colBase = (b % gx) * 64;
  const int ldk = (SPLITK > 0) ? 2 * SPLITK : K;
  const int kBase = kh * ((SPLITK > 0) ? SPLITK : 0);

  const bf16* aP[2]; const bf16* bP[2]; int off[2];
#pragma unroll
  for (int r = 0; r < 2; ++r) {
    const int c = wave * 2 + r;
    const int elem = c * 512 + lane * 8;
    const int s = elem >> 11, row = (elem >> 5) & 63, kp = elem & 31;
    aP[r] = A + (size_t)(rowBase + row) * ldk + kBase + s * 32 + kp;
    bP[r] = BT + (size_t)(colBase + row) * ldk + kBase + s * 32 + kp;
    off[r] = c * 512;
  }
  auto stage = [&](int kk, int buf) {
#pragma unroll
    for (int r = 0; r < 2; ++r) {
      __builtin_amdgcn_global_load_lds(
          (const __attribute__((address_space(1))) void*)(aP[r] + kk),
          (__attribute__((address_space(3))) void*)(&As[buf][off[r]]), 16, 0, 0);
      __builtin_amdgcn_global_load_lds(
          (const __attribute__((address_space(1))) void*)(bP[r] + kk),
          (__attribute__((address_space(3))) void*)(&Bs[buf][off[r]]), 16, 0, 0);
    }
  };

  f32x4 acc[2][2] = {};
  const int niter = K >> 6;
  stage(0, 0);
  for (int it = 0; it < niter; ++it) {
    const int cur = it & 1;
    __syncthreads();
    if (it + 1 < niter) stage((it + 1) << 6, cur ^ 1);
    const bf16* as = As[cur];
    const bf16* bs = Bs[cur];
#pragma unroll
    for (int s = 0; s < 2; ++s) {
      bf16x8 af[2], bfr[2];
#pragma unroll
      for (int i = 0; i < 2; ++i)
        af[i] = *(const bf16x8*)(as + s * 2048 + (wm * 32 + i * 16 + lr) * 32 + kg * 8);
#pragma unroll
      for (int j = 0; j < 2; ++j)
        bfr[j] = *(const bf16x8*)(bs + s * 2048 + (wn * 32 + j * 16 + lr) * 32 + kg * 8);
#pragma unroll
      for (int i = 0; i < 2; ++i)
#pragma unroll
        for (int j = 0; j < 2; ++j)
          acc[i][j] = __builtin_amdgcn_mfma_f32_16x16x32_bf16(af[i], bfr[j],
                                                              acc[i][j], 0, 0, 0);
    }
  }

  if (SPLITK > 0) {
    // atomic f32 accumulate into outF (holds residual already)
#pragma unroll
    for (int j = 0; j < 2; ++j) {
      const int col = colBase + wn * 32 + j * 16 + lr;
      const float bs = (kh == 0) ? bias[col] : 0.0f;
#pragma unroll
      for (int i = 0; i < 2; ++i)
#pragma unroll
        for (int r = 0; r < 4; ++r) {
          const size_t row = rowBase + wm * 32 + i * 16 + kg * 4 + r;
          unsafeAtomicAdd(&outF[row * N + col], acc[i][j][r] + bs);
        }
    }
    return;
  }

  if (MODE == 4 && colBase >= 1024) {
    // V region (block-uniform): write transposed into vT[(col-1024)][row]
#pragma unroll
    for (int j = 0; j < 2; ++j) {
      const int col = colBase + wn * 32 + j * 16 + lr;
      const float bs = bias[col];
      bf16* dst = vT + (size_t)(col - 1024) * S_LEN;
#pragma unroll
      for (int i = 0; i < 2; ++i) {
        bf16x4 p;
#pragma unroll
        for (int r = 0; r < 4; ++r) p[r] = (bf16)(acc[i][j][r] + bs);
        *(bf16x4*)(dst + rowBase + wm * 32 + i * 16 + kg * 4) = p;
      }
    }
    return;
  }

  // ---- vectorized epilogue: repack 64x64 tile through LDS ----
  __syncthreads();                 // all waves done reading As
  bf16* Cs = (bf16*)As;            // 8 KB scratch
#pragma unroll
  for (int j = 0; j < 2; ++j) {
    const int colL = wn * 32 + j * 16 + lr;
    const float bs = bias[colBase + colL];
#pragma unroll
    for (int i = 0; i < 2; ++i)
#pragma unroll
      for (int r = 0; r < 4; ++r) {
        const int rowL = wm * 32 + i * 16 + kg * 4 + r;
        float v = acc[i][j][r] + bs;
        if (MODE == 2) v = 0.5f * v * (1.0f + erff(v * 0.70710678118654752f));
        Cs[rowL * 64 + colL] = (bf16)v;
      }
  }
  __syncthreads();
  {
    const int rowOut = tid >> 2, colOut = (tid & 3) * 16;
    const bf16x8 v0 = *(const bf16x8*)&Cs[rowOut * 64 + colOut];
    const bf16x8 v1 = *(const bf16x8*)&Cs[rowOut * 64 + colOut + 8];
    bf16* dst = Cb + (size_t)(rowBase + rowOut) * N + colBase + colOut;
    *(bf16x8*)dst = v0;
    *(bf16x8*)(dst + 8) = v1;
  }
}

// ---------------- mmB: 32x64 tile, BK=64, dbuf (out-proj) -------------------
// bias + residual(f32) -> f32 out AND bf16 out
__global__ __launch_bounds__(256) void mmB_kernel(const bf16* __restrict__ A,
                                                  const bf16* __restrict__ BT,
                                                  const float* __restrict__ bias,
                                                  const float* __restrict__ res,
                                                  float* __restrict__ Cf,
                                                  bf16* __restrict__ Cb,
                                                  int N, int K) {
  __shared__ bf16 As[2][32 * 64];
  __shared__ bf16 Bs[2][64 * 64];
  const int tid = threadIdx.x;
  const int wave = tid >> 6, lane = tid & 63;
  const int lr = lane & 15, kg = lane >> 4;
  const int rowBase = blockIdx.y * 32, colBase = blockIdx.x * 64;

  const bf16* aP; const bf16* bP[2]; int aOff, bOff[2];
  {
    const int elem = wave * 512 + lane * 8;
    const int s = elem >> 10, row = (elem >> 5) & 31, kp = elem & 31;
    aP = A + (size_t)(rowBase + row) * K + s * 32 + kp;
    aOff = wave * 512;
  }
#pragma unroll
  for (int r = 0; r < 2; ++r) {
    const int c = wave * 2 + r;
    const int elem = c * 512 + lane * 8;
    const int s = elem >> 11, row = (elem >> 5) & 63, kp = elem & 31;
    bP[r] = BT + (size_t)(colBase + row) * K + s * 32 + kp;
    bOff[r] = c * 512;
  }
  auto stage = [&](int kk, int buf) {
    __builtin_amdgcn_global_load_lds(
        (const __attribute__((address_space(1))) void*)(aP + kk),
        (__attribute__((address_space(3))) void*)(&As[buf][aOff]), 16, 0, 0);
#pragma unroll
    for (int r = 0; r < 2; ++r)
      __builtin_amdgcn_global_load_lds(
          (const __attribute__((address_space(1))) void*)(bP[r] + kk),
          (__attribute__((address_space(3))) void*)(&Bs[buf][bOff[r]]), 16, 0, 0);
  };

  f32x4 acc[2] = {};
  const int niter = K >> 6;
  stage(0, 0);
  for (int it = 0; it < niter; ++it) {
    const int cur = it & 1;
    __syncthreads();
    if (it + 1 < niter) stage((it + 1) << 6, cur ^ 1);
    const bf16* as = As[cur];
    const bf16* bs = Bs[cur];
#pragma unroll
    for (int s = 0; s < 2; ++s) {
      bf16x8 af[2], bfr;
#pragma unroll
      for (int i = 0; i < 2; ++i)
        af[i] = *(const bf16x8*)(as + s * 1024 + (i * 16 + lr) * 32 + kg * 8);
      bfr = *(const bf16x8*)(bs + s * 2048 + (wave * 16 + lr) * 32 + kg * 8);
#pragma unroll
      for (int i = 0; i < 2; ++i)
        acc[i] = __builtin_amdgcn_mfma_f32_16x16x32_bf16(af[i], bfr, acc[i], 0, 0, 0);
    }
  }

  {
    const int col = colBase + wave * 16 + lr;
    const float bs = bias[col];
#pragma unroll
    for (int i = 0; i < 2; ++i)
#pragma unroll
      for (int r = 0; r < 4; ++r) {
        const size_t row = rowBase + i * 16 + kg * 4 + r;
        const float v = acc[i][r] + bs + res[row * N + col];
        Cf[row * N + col] = v;
        Cb[row * N + col] = (bf16)v;
      }
  }
}

// ---------------- fused MFMA local attention (unchanged, verified) ----------
__global__ __launch_bounds__(256) void attn_fused(const bf16* __restrict__ qkvb,
                                                  const bf16* __restrict__ vT,
                                                  bf16* __restrict__ attnb) {
  __shared__ bf16 Kl[192][72];
  __shared__ bf16 Vt[64][200];
  __shared__ bf16 Ql[64][72];

  const int tid = threadIdx.x;
  const int s0 = blockIdx.x * 64;
  const int hc = blockIdx.y * DHEAD;

  {
    const int row = tid >> 2, c0 = (tid & 3) * 16;
    const bf16* src = qkvb + (size_t)(s0 + row) * 1536 + hc + c0;
    *(bf16x8*)&Ql[row][c0] = *(const bf16x8*)src;
    *(bf16x8*)&Ql[row][c0 + 8] = *(const bf16x8*)(src + 8);
  }
#pragma unroll
  for (int it = 0; it < 3; it++) {
    const int row = it * 64 + (tid >> 2), c0 = (tid & 3) * 16;
    const int p = s0 - 64 + row;
    bf16x8 a, b;
    if (p >= 0 && p < S_LEN) {
      const bf16* src = qkvb + (size_t)p * 1536 + 512 + hc + c0;
      a = *(const bf16x8*)src;
      b = *(const bf16x8*)(src + 8);
    } else {
#pragma unroll
      for (int j = 0; j < 8; j++) { a[j] = (bf16)0.f; b[j] = (bf16)0.f; }
    }
    *(bf16x8*)&Kl[row][c0] = a;
    *(bf16x8*)&Kl[row][c0 + 8] = b;
  }
  {
    const int d = tid >> 2, r0 = (tid & 3) * 48;
    const bf16* src = vT + (size_t)(hc + d) * S_LEN;
#pragma unroll
    for (int i = 0; i < 6; i++) {
      const int p0 = s0 - 64 + r0 + i * 8;
      bf16x8 v;
      if (p0 >= 0 && p0 + 8 <= S_LEN) {
        v = *(const bf16x8*)(src + p0);
      } else {
#pragma unroll
        for (int j = 0; j < 8; j++) {
          const int p = p0 + j;
          v[j] = (p >= 0 && p < S_LEN) ? src[p] : (bf16)0.f;
        }
      }
      *(bf16x8*)&Vt[d][r0 + i * 8] = v;
    }
  }
  __syncthreads();

  const int wv = tid >> 6, lane = tid & 63;
  const int lr = lane & 15, kg = lane >> 4;

  f32x4 c[12] = {};
#pragma unroll
  for (int step = 0; step < 2; step++) {
    const bf16x8 qf = *(const bf16x8*)&Ql[wv * 16 + lr][step * 32 + kg * 8];
#pragma unroll
    for (int t = 0; t < 12; t++) {
      const bf16x8 kf = *(const bf16x8*)&Kl[t * 16 + lr][step * 32 + kg * 8];
      c[t] = __builtin_amdgcn_mfma_f32_16x16x32_bf16(qf, kf, c[t], 0, 0, 0);
    }
  }

  float e[12][4];
  float inv[4];
#pragma unroll
  for (int rr = 0; rr < 4; rr++) {
    const int q = wv * 16 + kg * 4 + rr;
    float m = -1e30f;
#pragma unroll
    for (int t = 0; t < 12; t++) {
      const int col = t * 16 + lr;
      if (col >= q && col <= q + 128) m = fmaxf(m, c[t][rr] * 0.125f);
    }
#pragma unroll
    for (int off = 1; off < 16; off <<= 1) m = fmaxf(m, __shfl_xor(m, off));
    float sum = 0.f;
#pragma unroll
    for (int t = 0; t < 12; t++) {
      const int col = t * 16 + lr;
      const bool valid = (col >= q) && (col <= q + 128);
      const float ev = valid ? __expf(c[t][rr] * 0.125f - m) : 0.f;
      e[t][rr] = ev;
      sum += ev;
    }
#pragma unroll
    for (int off = 1; off < 16; off <<= 1) sum += __shfl_xor(sum, off);
    inv[rr] = 1.f / sum;
  }

  __syncthreads();

  bf16* Pl = (bf16*)Kl + wv * (16 * 200);
#pragma unroll
  for (int rr = 0; rr < 4; rr++)
#pragma unroll
    for (int t = 0; t < 12; t++)
      Pl[(kg * 4 + rr) * 200 + t * 16 + lr] = (bf16)(e[t][rr] * inv[rr]);

  f32x4 o[4] = {};
#pragma unroll
  for (int step = 0; step < 6; step++) {
    const bf16x8 pf = *(const bf16x8*)&Pl[lr * 200 + step * 32 + kg * 8];
#pragma unroll
    for (int jt = 0; jt < 4; jt++) {
      const bf16x8 vf = *(const bf16x8*)&Vt[jt * 16 + lr][step * 32 + kg * 8];
      o[jt] = __builtin_amdgcn_mfma_f32_16x16x32_bf16(pf, vf, o[jt], 0, 0, 0);
    }
  }

#pragma unroll
  for (int jt = 0; jt < 4; jt++)
#pragma unroll
    for (int rr = 0; rr < 4; rr++) {
      const int q = wv * 16 + kg * 4 + rr;
      attnb[(size_t)(s0 + q) * DMODEL + hc + jt * 16 + lr] = (bf16)o[jt][rr];
    }
}

// ---------------- launch ----------------
extern "C" void kernel_launch(void* const* d_in, const int* in_sizes, int n_in,
                              void* d_out, int out_size, void* d_ws, size_t ws_size,
                              hipStream_t stream) {
  const float* x     = (const float*)d_in[0];
  const float* w_qkv = (const float*)d_in[1];
  const float* b_qkv = (const float*)d_in[2];
  const float* w_out = (const float*)d_in[3];
  const float* b_out = (const float*)d_in[4];
  const float* ln_g  = (const float*)d_in[5];
  const float* ln_b  = (const float*)d_in[6];
  const float* w1    = (const float*)d_in[7];
  const float* b1    = (const float*)d_in[8];
  const float* w2    = (const float*)d_in[9];
  const float* b2    = (const float*)d_in[10];
  float* out = (float*)d_out;

  char* w = (char*)d_ws;
  const size_t MB = 1u << 20;
  bf16* xn    = (bf16*)(w + 0);           // [0,2) MB
  bf16* attnb = (bf16*)(w + 0);           // alias xn (dead after QKV)
  bf16* qkvb  = (bf16*)(w + 2 * MB);      // [2,8) MB
  bf16* outb  = (bf16*)(w + 2 * MB);      // alias qkvb (dead after attention)
  bf16* vT    = (bf16*)(w + 8 * MB);      // [8,10) MB
  bf16* h1    = (bf16*)(w + 10 * MB);     // [10,18) MB
  bf16* wqkvT = (bf16*)(w + 18 * MB);     // 1.5 MB
  bf16* woutT = (bf16*)(w + 19 * MB + 512 * 1024);  // 0.5 MB
  bf16* w1T   = (bf16*)(w + 20 * MB);     // 2 MB
  bf16* w2T   = (bf16*)(w + 22 * MB);     // 2 MB

  // 1. prep: LN (2048) + all weight transposes (3072)
  prep_kernel<<<5120, 256, 0, stream>>>(x, ln_g, ln_b, w_qkv, w_out, w1, w2,
                                        xn, wqkvT, woutT, w1T, w2T);
  // 2. QKV: 64x64 tiles, 768 blocks; V cols -> vT transposed
  mmC_kernel<4, 0><<<768, 256, 0, stream>>>(xn, wqkvT, b_qkv, qkvb, vT,
                                            nullptr, 1536, 512, 24);
  // 3. fused attention
  attn_fused<<<dim3(32, 8), 256, 0, stream>>>(qkvb, vT, attnb);
  // 4. out-proj + residual(x) -> f32 out + bf16 outb (512 blocks)
  mmB_kernel<<<dim3(8, 64), 256, 0, stream>>>(attnb, woutT, b_out, x, out,
                                              outb, 512, 512);
  // 5. FFN1 + GELU -> bf16 h1 (1024 blocks)
  mmC_kernel<2, 0><<<1024, 256, 0, stream>>>(outb, w1T, b1, h1, nullptr,
                                             nullptr, 2048, 512, 32);
  // 6. FFN2 split-K=2, atomic accumulate into d_out (holds residual; 512 blocks)
  mmC_kernel<2, 1024><<<512, 256, 0, stream>>>(h1, w2T, b2, nullptr, nullptr,
                                               out, 512, 1024, 8);
}